// Round 2
// baseline (380.672 us; speedup 1.0000x reference)
//
#include <hip/hip_runtime.h>

// Problem constants (fixed by the reference):
#define E_ENV  8192
#define A_AG   128
#define K_PASS 512
#define ROW_F  11
#define SLICE_F  (K_PASS * ROW_F)   // 5632 floats per env slice (divisible by 4)
#define SLICE_V4 (SLICE_F / 4)      // 1408 float4 per env slice
#define ITERS    (SLICE_V4 / A_AG)  // 11 float4s per thread

// ---------------------------------------------------------------------------
// Single fused kernel, one block (128 threads, 2 waves) per env.
//
//  Phase 0: issue ALL 11 float4 slice loads into registers up front --
//           their HBM latency hides under the whole resolve phase.
//  Phase 1: stage + resolve duplicate accepts (one pass of the reference
//           while_loop suffices: the body keeps only the single env-wide
//           argmin among dup agents, killing every other dup in one shot).
//  Phase 2: store the 11 registers back unmodified (pure stream, no VALU
//           between load and store -> full ILP, no per-iter vmcnt stalls).
//  Phase 3: after __syncthreads (vmcnt(0) drain -> block-ordered stores),
//           patch the few touched rows with scattered dword stores. The
//           lines were written by this block microseconds ago -> L2-hot,
//           no HBM read-modify-write.
//
// Targets are env-partitioned, so all conflict state is env-local; no
// cross-block races.
// ---------------------------------------------------------------------------
__global__ __launch_bounds__(128) void k_fused(
    const float4* __restrict__ pass4,
    const int*    __restrict__ accepts,
    const int*    __restrict__ picks,
    const int*    __restrict__ targets,
    const float4* __restrict__ vectors,
    const int*    __restrict__ timesteps,
    float4*       __restrict__ out4,
    float*        __restrict__ out)
{
    __shared__ int           cnt[K_PASS];      // dup counter per local passenger
    __shared__ int           agentOf[K_PASS];  // surviving accept agent, -1 none
    __shared__ unsigned char pickF[K_PASS];    // pick succeeded flag
    __shared__ float swv[2];
    __shared__ int   swi[2];

    const int e   = blockIdx.x;
    const int a   = threadIdx.x;            // agent 0..127
    const int gid = e * A_AG + a;

    // ---- phase 0: prefetch the whole env slice into registers ----
    const float4* src = pass4 + (size_t)e * SLICE_V4;
    float4*       dst = out4  + (size_t)e * SLICE_V4;
    float4 x[ITERS];
    #pragma unroll
    for (int it = 0; it < ITERS; ++it)
        x[it] = src[a + it * A_AG];

    // phase-1 inputs (issue early, consumed after the barrier)
    float4 v = vectors[gid];
    const int  t    = targets[gid];          // global passenger id in [e*K,(e+1)*K)
    const bool acc  = accepts[gid] != 0;
    const bool pick = picks[gid] != 0;

    // zero the per-env overlay
    #pragma unroll
    for (int j = 0; j < K_PASS / A_AG; ++j) {
        cnt[a + j * A_AG]     = 0;
        agentOf[a + j * A_AG] = -1;
        pickF[a + j * A_AG]   = 0;
    }
    __syncthreads();

    // ---- phase 1: stage ----
    bool invalid = (v.x == -100.0f) && (v.y == -100.0f) &&
                   (v.z == -100.0f) && (v.w == -100.0f);
    float dx = v.x - v.z, dy = v.y - v.w;
    float d = sqrtf(dx * dx + dy * dy);
    if (invalid) d = INFINITY;

    const int tl = t - e * K_PASS;           // local 0..511

    int at = acc ? t : -100;
    if (at >= 0) atomicAdd(&cnt[tl], 1);
    __syncthreads();

    // ---- resolve (single iteration of the reference while_loop) ----
    bool dup = (at >= 0) && (cnt[tl] > 1);
    float bv = dup ? d : INFINITY;
    int   bi = a;

    // wave-64 butterfly argmin, first-index tie-break
    #pragma unroll
    for (int off = 32; off > 0; off >>= 1) {
        float ov = __shfl_xor(bv, off);
        int   oi = __shfl_xor(bi, off);
        if (ov < bv || (ov == bv && oi < bi)) { bv = ov; bi = oi; }
    }
    int wave = a >> 6;
    if ((a & 63) == 0) { swv[wave] = bv; swi[wave] = bi; }
    __syncthreads();
    float v0 = swv[0], v1 = swv[1];
    int   i0 = swi[0], i1 = swi[1];
    // tie -> smaller index (wave 0) wins: matches jnp.argmin first-index
    int bidx = (v1 < v0 || (v1 == v0 && i1 < i0)) ? i1 : i0;

    int f = (dup && a != bidx) ? -100 : at;

    // build overlay: at most one surviving accept per passenger -> plain store
    if (f >= 0) agentOf[tl] = a;
    // multi-writers store the same value: benign
    if (pick && d < 1e-6f) pickF[tl] = 1;

    // ---- phase 2: pure streaming store of the slice ----
    #pragma unroll
    for (int it = 0; it < ITERS; ++it)
        dst[a + it * A_AG] = x[it];

    // vmcnt(0) drain + barrier: copy stores ordered before patch stores,
    // and the overlay (LDS) is complete for all threads.
    __syncthreads();

    // ---- phase 3: scattered patch of touched rows (L2-hot lines) ----
    const float tsf = (float)timesteps[e];
    #pragma unroll
    for (int j = 0; j < K_PASS / A_AG; ++j) {
        int p  = a + j * A_AG;
        int ag = agentOf[p];
        bool pk = pickF[p] != 0;
        if (ag >= 0 || pk) {
            size_t b = ((size_t)e * K_PASS + p) * ROW_F;
            out[b + 6] = pk ? 2.0f : 1.0f;       // pick overrides accept
            if (ag >= 0) {
                out[b + 7] = (float)ag;
                out[b + 9] = tsf;
            }
            if (pk) out[b + 10] = tsf;
        }
    }
}

// ---------------------------------------------------------------------------
extern "C" void kernel_launch(void* const* d_in, const int* in_sizes, int n_in,
                              void* d_out, int out_size, void* d_ws, size_t ws_size,
                              hipStream_t stream)
{
    const float* passengers = (const float*)d_in[0];
    const int*   accepts    = (const int*)d_in[1];
    const int*   picks      = (const int*)d_in[2];
    const int*   targets    = (const int*)d_in[3];
    const float* vectors    = (const float*)d_in[4];
    const int*   timesteps  = (const int*)d_in[5];
    float*       out        = (float*)d_out;

    k_fused<<<E_ENV, A_AG, 0, stream>>>(
        (const float4*)passengers, accepts, picks, targets,
        (const float4*)vectors, timesteps, (float4*)out, out);
}

// Round 3
// 359.724 us; speedup vs baseline: 1.0582x; 1.0582x over previous
//
#include <hip/hip_runtime.h>

// Problem constants (fixed by the reference):
#define E_ENV  8192
#define A_AG   128
#define K_PASS 512
#define ROW_F  11
#define SLICE_F  (K_PASS * ROW_F)   // 5632 floats per env slice (divisible by 4)
#define SLICE_V4 (SLICE_F / 4)      // 1408 float4 per env slice
#define ITERS    (SLICE_V4 / A_AG)  // 11 float4s per thread

// ---------------------------------------------------------------------------
// Single fused kernel, one block (128 threads, 2 waves) per env.
//
//  Phase 0: issue resolve inputs, then ALL 11 slice float4 loads, then PIN
//           them in VGPRs with an empty asm ("+v" on every component).
//           Round-2 evidence (VGPR_Count=32) showed the compiler otherwise
//           sinks these __restrict__ loads back into the store loop, leaving
//           only 1 load in flight per wave (2.3 TB/s). Pinned: 11 KB
//           outstanding per wave, ~176 KB/CU >> 22 KB BDP -> BW-bound.
//  Phase 1: stage + resolve duplicate accepts (one pass of the reference
//           while_loop suffices: the body keeps only the single env-wide
//           argmin among dup agents, killing every other dup in one shot).
//  Phase 2: store the slice with the patch applied INLINE (each output
//           line written exactly once -- round 2 showed patch-after-stream
//           doubles WRITE_SIZE via L2-evicted RMW).
//
// Targets are env-partitioned, so all conflict state is env-local; no
// cross-block races.
// ---------------------------------------------------------------------------
__global__ __launch_bounds__(128) void k_fused(
    const float4* __restrict__ pass4,
    const int*    __restrict__ accepts,
    const int*    __restrict__ picks,
    const int*    __restrict__ targets,
    const float4* __restrict__ vectors,
    const int*    __restrict__ timesteps,
    float4*       __restrict__ out4)
{
    __shared__ int cnt[K_PASS];      // dup counter per local passenger
    __shared__ int agentOf[K_PASS];  // surviving accept agent, -1 none
    __shared__ int pickF[K_PASS];    // pick succeeded flag
    __shared__ float swv[2];
    __shared__ int   swi[2];

    const int e   = blockIdx.x;
    const int a   = threadIdx.x;            // agent 0..127
    const int gid = e * A_AG + a;

    // ---- phase 0a: resolve inputs first (so the pin's wait covers them) ----
    float4 v = vectors[gid];
    const int  t    = targets[gid];          // global passenger id in [e*K,(e+1)*K)
    const bool acc  = accepts[gid] != 0;
    const bool pick = picks[gid] != 0;
    const float tsf = (float)timesteps[e];

    // ---- phase 0b: slice loads, all 11 in flight ----
    const float4* src = pass4 + (size_t)e * SLICE_V4;
    float4*       dst = out4  + (size_t)e * SLICE_V4;
    float4 x[ITERS];
    #pragma unroll
    for (int it = 0; it < ITERS; ++it)
        x[it] = src[a + it * A_AG];

    // ---- pin: force all loads issued & materialized HERE, not in the loop ----
    #pragma unroll
    for (int it = 0; it < ITERS; ++it)
        asm volatile("" : "+v"(x[it].x), "+v"(x[it].y), "+v"(x[it].z), "+v"(x[it].w));

    // zero the per-env overlay
    #pragma unroll
    for (int j = 0; j < K_PASS / A_AG; ++j) {
        cnt[a + j * A_AG]     = 0;
        agentOf[a + j * A_AG] = -1;
        pickF[a + j * A_AG]   = 0;
    }
    __syncthreads();

    // ---- phase 1: stage ----
    bool invalid = (v.x == -100.0f) && (v.y == -100.0f) &&
                   (v.z == -100.0f) && (v.w == -100.0f);
    float dx = v.x - v.z, dy = v.y - v.w;
    float d = sqrtf(dx * dx + dy * dy);
    if (invalid) d = INFINITY;

    const int tl = t - e * K_PASS;           // local 0..511

    int at = acc ? t : -100;
    if (at >= 0) atomicAdd(&cnt[tl], 1);
    __syncthreads();

    // ---- resolve (single iteration of the reference while_loop) ----
    bool dup = (at >= 0) && (cnt[tl] > 1);
    float bv = dup ? d : INFINITY;
    int   bi = a;

    // wave-64 butterfly argmin, first-index tie-break
    #pragma unroll
    for (int off = 32; off > 0; off >>= 1) {
        float ov = __shfl_xor(bv, off);
        int   oi = __shfl_xor(bi, off);
        if (ov < bv || (ov == bv && oi < bi)) { bv = ov; bi = oi; }
    }
    int wave = a >> 6;
    if ((a & 63) == 0) { swv[wave] = bv; swi[wave] = bi; }
    __syncthreads();
    float v0 = swv[0], v1 = swv[1];
    int   i0 = swi[0], i1 = swi[1];
    // tie -> smaller index (wave 0) wins: matches jnp.argmin first-index
    int bidx = (v1 < v0 || (v1 == v0 && i1 < i0)) ? i1 : i0;

    int f = (dup && a != bidx) ? -100 : at;

    // build overlay: at most one surviving accept per passenger -> plain store
    if (f >= 0) agentOf[tl] = a;
    // multi-writers store the same value: benign
    if (pick && d < 1e-6f) pickF[tl] = 1;
    __syncthreads();   // overlay complete & visible

    // ---- phase 2: streaming store with inline patch ----
    auto patch = [&](float val, unsigned row, int col) -> float {
        int  ag = agentOf[row];
        bool pk = pickF[row] != 0;
        if (col == 6) {
            if (pk) return 2.0f;               // pick overrides accept
            if (ag >= 0) return 1.0f;
        } else if (col == 7) {
            if (ag >= 0) return (float)ag;
        } else if (col == 9) {
            if (ag >= 0) return tsf;
        } else if (col == 10) {
            if (pk) return tsf;
        }
        return val;
    };

    #pragma unroll
    for (int it = 0; it < ITERS; ++it) {
        int idx = a + it * A_AG;                  // float4 index within slice
        float4 y = x[it];
        unsigned g   = (unsigned)idx * 4u;        // element index 0..5631
        unsigned row = g / 11u;                   // magic-mul, cheap
        int      col = (int)(g - row * 11u);
        y.x = patch(y.x, row, col); if (++col == 11) { col = 0; ++row; }
        y.y = patch(y.y, row, col); if (++col == 11) { col = 0; ++row; }
        y.z = patch(y.z, row, col); if (++col == 11) { col = 0; ++row; }
        y.w = patch(y.w, row, col);
        dst[idx] = y;
    }
}

// ---------------------------------------------------------------------------
extern "C" void kernel_launch(void* const* d_in, const int* in_sizes, int n_in,
                              void* d_out, int out_size, void* d_ws, size_t ws_size,
                              hipStream_t stream)
{
    const float* passengers = (const float*)d_in[0];
    const int*   accepts    = (const int*)d_in[1];
    const int*   picks      = (const int*)d_in[2];
    const int*   targets    = (const int*)d_in[3];
    const float* vectors    = (const float*)d_in[4];
    const int*   timesteps  = (const int*)d_in[5];
    float*       out        = (float*)d_out;

    k_fused<<<E_ENV, A_AG, 0, stream>>>(
        (const float4*)passengers, accepts, picks, targets,
        (const float4*)vectors, timesteps, (float4*)out);
}

// Round 4
// 349.199 us; speedup vs baseline: 1.0901x; 1.0301x over previous
//
#include <hip/hip_runtime.h>

// Problem constants (fixed by the reference):
#define E_ENV  8192
#define A_AG   128
#define K_PASS 512
#define ROW_F  11
#define SLICE_F  (K_PASS * ROW_F)   // 5632 floats per env slice (divisible by 4)
#define SLICE_V4 (SLICE_F / 4)      // 1408 float4 per env slice
#define ITERS    (SLICE_V4 / A_AG)  // 11 float4s per thread

// Overlay encoding (one int per local passenger):
//   bit 9 = pick succeeded, bit 8 = accepted, bits 6..0 = winning agent id
#define OV_PICK 0x200
#define OV_ACC  0x100

// ---------------------------------------------------------------------------
// Single fused kernel, one block (128 threads, 2 waves) per env.
//
// History of the latency bug this version fixes:
//   r1: load->patch->store chain, 1 load in flight/wave      -> 2.3 TB/s
//   r2: prefetch w/o pin: compiler sank loads (VGPR=32), and
//       patch-after-stream doubled WRITE via L2-evicted RMW  -> 3.9 TB/s, 2x traffic
//   r3: per-value asm pin: load+pin pairs sank TOGETHER past
//       the barriers (VGPR still 32)                         -> 2.1 TB/s
// Fix: ONE asm volatile "memory" clobber after the load batch. Opaque to
// alias analysis -> no load may sink below it. Loads all issue up front;
// their latency hides under the whole resolve phase; the patch loop then
// runs back-to-back stores. __launch_bounds__(128,4) caps VGPR at 128 so
// the 44 live registers don't spill.
// ---------------------------------------------------------------------------
__global__ __launch_bounds__(128, 4) void k_fused(
    const float4* __restrict__ pass4,
    const int*    __restrict__ accepts,
    const int*    __restrict__ picks,
    const int*    __restrict__ targets,
    const float4* __restrict__ vectors,
    const int*    __restrict__ timesteps,
    float4*       __restrict__ out4)
{
    __shared__ int cnt[K_PASS];      // dup counter per local passenger
    __shared__ int ov[K_PASS];       // packed overlay (OV_* bits)
    __shared__ float swv[2];
    __shared__ int   swi[2];

    const int e   = blockIdx.x;
    const int a   = threadIdx.x;            // agent 0..127
    const int gid = e * A_AG + a;

    // ---- phase 0a: resolve inputs (their waits overlap the slice loads) ----
    float4 v = vectors[gid];
    const int  t    = targets[gid];          // global passenger id in [e*K,(e+1)*K)
    const bool acc  = accepts[gid] != 0;
    const bool pick = picks[gid] != 0;
    const float tsf = (float)timesteps[e];

    // ---- phase 0b: all 11 slice loads issued back-to-back ----
    const float4* src = pass4 + (size_t)e * SLICE_V4;
    float4*       dst = out4  + (size_t)e * SLICE_V4;
    float4 x[ITERS];
    #pragma unroll
    for (int it = 0; it < ITERS; ++it)
        x[it] = src[a + it * A_AG];

    // Compiler memory barrier: no load may sink below this point.
    asm volatile("" ::: "memory");

    // zero the per-env overlay
    #pragma unroll
    for (int j = 0; j < K_PASS / A_AG; ++j) {
        cnt[a + j * A_AG] = 0;
        ov [a + j * A_AG] = 0;
    }
    __syncthreads();

    // ---- phase 1: stage ----
    bool invalid = (v.x == -100.0f) && (v.y == -100.0f) &&
                   (v.z == -100.0f) && (v.w == -100.0f);
    float dx = v.x - v.z, dy = v.y - v.w;
    float d = sqrtf(dx * dx + dy * dy);
    if (invalid) d = INFINITY;

    const int tl = t - e * K_PASS;           // local 0..511

    int at = acc ? t : -100;
    if (at >= 0) atomicAdd(&cnt[tl], 1);
    __syncthreads();

    // ---- resolve (single iteration of the reference while_loop: the body
    //       keeps only the env-wide argmin among ALL dup agents, killing
    //       every other dup in one shot -> loop terminates after one pass) ----
    bool dup = (at >= 0) && (cnt[tl] > 1);
    float bv = dup ? d : INFINITY;
    int   bi = a;

    // wave-64 butterfly argmin, first-index tie-break
    #pragma unroll
    for (int off = 32; off > 0; off >>= 1) {
        float ovv = __shfl_xor(bv, off);
        int   oii = __shfl_xor(bi, off);
        if (ovv < bv || (ovv == bv && oii < bi)) { bv = ovv; bi = oii; }
    }
    int wave = a >> 6;
    if ((a & 63) == 0) { swv[wave] = bv; swi[wave] = bi; }
    __syncthreads();
    float v0 = swv[0], v1 = swv[1];
    int   i0 = swi[0], i1 = swi[1];
    // tie -> smaller index (wave 0) wins: matches jnp.argmin first-index
    int bidx = (v1 < v0 || (v1 == v0 && i1 < i0)) ? i1 : i0;

    int f = (dup && a != bidx) ? -100 : at;

    // build packed overlay (atomicOr: accept-winner and pick may be
    // different threads hitting the same passenger)
    if (f >= 0)            atomicOr(&ov[tl], OV_ACC | a);
    if (pick && d < 1e-6f) atomicOr(&ov[tl], OV_PICK);
    __syncthreads();   // overlay complete & visible

    // ---- phase 2: streaming store with inline patch ----
    auto patch = [&](float val, unsigned row, int col) -> float {
        int o = ov[row];
        if (col == 6) {
            if (o & OV_PICK) return 2.0f;          // pick overrides accept
            if (o & OV_ACC)  return 1.0f;
        } else if (col == 7) {
            if (o & OV_ACC)  return (float)(o & 0x7f);
        } else if (col == 9) {
            if (o & OV_ACC)  return tsf;
        } else if (col == 10) {
            if (o & OV_PICK) return tsf;
        }
        return val;
    };

    #pragma unroll
    for (int it = 0; it < ITERS; ++it) {
        int idx = a + it * A_AG;                  // float4 index within slice
        float4 y = x[it];
        unsigned g   = (unsigned)idx * 4u;        // element index 0..5631
        unsigned row = g / 11u;                   // magic-mul, cheap
        int      col = (int)(g - row * 11u);
        y.x = patch(y.x, row, col); if (++col == 11) { col = 0; ++row; }
        y.y = patch(y.y, row, col); if (++col == 11) { col = 0; ++row; }
        y.z = patch(y.z, row, col); if (++col == 11) { col = 0; ++row; }
        y.w = patch(y.w, row, col);
        dst[idx] = y;
    }
}

// ---------------------------------------------------------------------------
extern "C" void kernel_launch(void* const* d_in, const int* in_sizes, int n_in,
                              void* d_out, int out_size, void* d_ws, size_t ws_size,
                              hipStream_t stream)
{
    const float* passengers = (const float*)d_in[0];
    const int*   accepts    = (const int*)d_in[1];
    const int*   picks      = (const int*)d_in[2];
    const int*   targets    = (const int*)d_in[3];
    const float* vectors    = (const float*)d_in[4];
    const int*   timesteps  = (const int*)d_in[5];
    float*       out        = (float*)d_out;

    k_fused<<<E_ENV, A_AG, 0, stream>>>(
        (const float4*)passengers, accepts, picks, targets,
        (const float4*)vectors, timesteps, (float4*)out);
}